// Round 9
// baseline (6610.075 us; speedup 1.0000x reference)
//
#include <hip/hip_runtime.h>
#include <cstdint>
#include <cstddef>

typedef unsigned short ubf;   // bf16 bit pattern (internal use only)
typedef unsigned int   u32;
typedef __attribute__((ext_vector_type(8))) short short8;
typedef __attribute__((ext_vector_type(4))) float f32x4;
typedef __attribute__((ext_vector_type(4))) float f4v;
typedef __attribute__((ext_vector_type(2))) float f2v;
typedef __attribute__((ext_vector_type(4))) unsigned short us4;

#define NEG_INF_F (-1000000000.0f)
#define FOURH 2048

// d_out element offsets in FLOAT32 elements (model confirmed by r8 probe:
// d_out is f32, chunks carved in f32 elements, ref bf16-rounded).
#define ENC_SEG   8388608            // 64*256*512
#define REC_OFF   25165824
#define REC_SEG   8192000            // 64*256*500
#define MASK_OFF  49741824
#define LOGB_OFF  49774592
#define SAMB_OFF  49807360
#define LOGZ_OFF  49856512
#define SAMZ_OFF  49881088

// scratch inside recs[2] dead region: f32 elements [41,549,824 .. 49,741,824)
// relative offsets below (f32 elements from region base). zdec(seg2) writes row
// stripes at rel b*128000..+500 (b<64) and rec(seg2) fills t>=1 rows — both run
// AFTER every scratch user except rof, which zdec(seg2) reads and therefore
// sits in the stripe-free gap (896,500 .. 1,024,000).
#define SCR_P       0               // bf16[512][2048] = 2 MB = 524,288 f32
#define SCR_HBUF    524288          // bf16[2][4][16][512] = 32,768 f32
#define SCR_FLAGS   557056          // 1,024 f32 (u32 flags, 16-dword padded)
#define SCR_MASKF   558080          // 16,384 f32
#define SCR_LOGCUM  574464          // 16,384 f32
#define SCR_PART    590848          // 8*16,384 = 131,072 f32 (ends 721,920)
#define SCR_SBF     721920          // 16,384 f32 (ends 738,304)
#define SCR_ROF     960000          // 32,768 f32 (ends 992,768 < stripe b=8 @1,024,000)

__device__ __forceinline__ float bf2f(ubf u){
  union { u32 i; float f; } v; v.i = ((u32)u) << 16; return v.f;
}
__device__ __forceinline__ ubf f2bf(float f){
  union { float f; u32 i; } v; v.f = f;
  u32 x = v.i;
  u32 r = (x + 0x7FFFu + ((x >> 16) & 1u)) >> 16;   // RNE
  return (ubf)r;
}
__device__ __forceinline__ float sigm(float x){
  return 1.0f / (1.0f + __expf(-x));
}
__device__ __forceinline__ float tanh_fast(float x){
  x = fminf(fmaxf(x, -20.0f), 20.0f);
  float e2 = __expf(2.0f * x);
  return (e2 - 1.0f) / (e2 + 1.0f);
}

// ---------------------------------------------------------------- init flags
__global__ void init_kernel(u32* flags){
  int tid = threadIdx.x;
  #pragma unroll
  for (int i = 0; i < 4; i++) flags[tid + i*256] = 0u;
}

// ---------------------------------------------------------------- GEMM (MFMA 16x16x32 bf16)
// A: f32 (a_f32=1) or bf16 (a_f32=0). B: f32 weights. Staged into LDS as bf16.
// If wb2 == null: C(bf16) = op(A@B + bias), op = optional relu.
// If wb2 != null: part[(bn*2+wn)*16384 + m] = this slice's 128-col partial of
//                 relu(acc+bias) dot wb2  (deterministic, no atomics).
__global__ __launch_bounds__(256, 2) void gemm_kernel(
    const void* __restrict__ Aptr, int a_f32,
    const float* __restrict__ Bf, const float* __restrict__ bias,
    ubf* __restrict__ C, const float* __restrict__ wb2, float* __restrict__ part,
    int M, int N, int K, int relu, int mclamp)
{
  __shared__ __align__(16) ubf As[128*40];   // [128 rows][32 k + 8 pad]
  __shared__ __align__(16) ubf Bs[128*40];   // transposed: [128 n][32 k + 8 pad]
  int tid  = threadIdx.x;
  int bn   = blockIdx.x, bm = blockIdx.y;
  int w    = tid >> 6, lane = tid & 63, quad = lane >> 4, l16 = lane & 15;
  int wm   = w >> 1, wn = w & 1;

  f32x4 acc[4][4];
  #pragma unroll
  for (int i = 0; i < 4; i++)
    #pragma unroll
    for (int j = 0; j < 4; j++)
      #pragma unroll
      for (int r = 0; r < 4; r++) acc[i][j][r] = 0.0f;

  for (int k0 = 0; k0 < K; k0 += 32) {
    if (a_f32){
      const float* Af = (const float*)Aptr;
      #pragma unroll
      for (int h = 0; h < 4; h++){
        int v   = tid + h*256;          // 0..1023 float4 units
        int row = v >> 3, kc = (v & 7) * 4;
        int rm  = bm*128 + row;
        int ar  = rm < mclamp ? rm : mclamp;
        f4v q = *(const f4v*)(Af + (size_t)ar * K + k0 + kc);
        us4 s; s[0]=f2bf(q[0]); s[1]=f2bf(q[1]); s[2]=f2bf(q[2]); s[3]=f2bf(q[3]);
        *(us4*)&As[row*40 + kc] = s;
      }
    } else {
      const ubf* Ab = (const ubf*)Aptr;
      #pragma unroll
      for (int h = 0; h < 2; h++){
        int v   = tid + h*256;          // 0..511 vec8 units
        int row = v >> 2, kc = (v & 3) * 8;
        int rm  = bm*128 + row;
        int ar  = rm < mclamp ? rm : mclamp;
        uint4 q = *(const uint4*)(Ab + (size_t)ar * K + k0 + kc);
        *(uint4*)&As[row*40 + kc] = q;
      }
    }
    #pragma unroll
    for (int h = 0; h < 4; h++){
      int v  = tid + h*256;             // 0..1023 float4 units
      int kk = v >> 5, nn = (v & 31) * 4;
      f4v q = *(const f4v*)(Bf + (size_t)(k0 + kk) * N + bn*128 + nn);
      #pragma unroll
      for (int j = 0; j < 4; j++) Bs[(nn + j)*40 + kk] = f2bf(q[j]);
    }
    __syncthreads();
    short8 af[4], bfr[4];
    #pragma unroll
    for (int i = 0; i < 4; i++){
      int row = wm*64 + i*16 + l16;
      af[i]  = *(const short8*)&As[row*40 + quad*8];
      int col = wn*64 + i*16 + l16;
      bfr[i] = *(const short8*)&Bs[col*40 + quad*8];
    }
    #pragma unroll
    for (int i = 0; i < 4; i++)
      #pragma unroll
      for (int j = 0; j < 4; j++)
        acc[i][j] = __builtin_amdgcn_mfma_f32_16x16x32_bf16(af[i], bfr[j], acc[i][j], 0, 0, 0);
    __syncthreads();
  }
  // epilogue: C/D layout col=lane&15, row=quad*4+reg
  if (!wb2){
    #pragma unroll
    for (int i = 0; i < 4; i++){
      #pragma unroll
      for (int j = 0; j < 4; j++){
        int n   = bn*128 + wn*64 + j*16 + l16;
        float bv = bias ? bias[n] : 0.0f;
        #pragma unroll
        for (int r = 0; r < 4; r++){
          int m   = bm*128 + wm*64 + i*16 + quad*4 + r;
          float vv = acc[i][j][r] + bv;
          if (relu) vv = fmaxf(vv, 0.0f);
          C[(size_t)m * N + n] = f2bf(vv);
        }
      }
    }
  } else {
    #pragma unroll
    for (int i = 0; i < 4; i++){
      f32x4 rp;
      #pragma unroll
      for (int r = 0; r < 4; r++) rp[r] = 0.0f;
      #pragma unroll
      for (int j = 0; j < 4; j++){
        int n   = bn*128 + wn*64 + j*16 + l16;
        float bv = bias[n];
        float wv = wb2[n];
        #pragma unroll
        for (int r = 0; r < 4; r++)
          rp[r] += fmaxf(acc[i][j][r] + bv, 0.0f) * wv;
      }
      #pragma unroll
      for (int off = 1; off < 16; off <<= 1)
        #pragma unroll
        for (int r = 0; r < 4; r++)
          rp[r] += __shfl_xor(rp[r], off, 64);
      if (l16 == 0){
        #pragma unroll
        for (int r = 0; r < 4; r++){
          int m = bm*128 + wm*64 + i*16 + quad*4 + r;
          part[(size_t)(bn*2 + wn)*16384 + m] = rp[r];
        }
      }
    }
  }
}

// ---------------------------------------------------------------- persistent masked-LSTM
// 64 WGs = 4 batch-groups(16 batches) x 16 unit-groups(32 units); plain launch.
// Wh slice (f32 -> bf16) lives in VGPRs as persistent MFMA B-frags. Per-step sync:
// epoch flags (device-scope atomics); h double-buffered (bf16). enc out = f32.
__global__ __launch_bounds__(256, 1) void lstm_kernel(
    const ubf* __restrict__ Pt,      // [512(V pad)][4H] bf16, includes b_lstm
    const int* __restrict__ actions, // [B][T]
    const float* __restrict__ Whf,   // [H][4H] f32
    const float* __restrict__ mask,  // [B][T] f32 or null (seg 0)
    float* __restrict__ enc,         // d_out + seg*ENC_SEG (f32)
    ubf* hbuf,                       // scratch: [2][4][16][512] bf16
    u32* flags,                      // scratch: [64]x16-dword-padded
    int seg)
{
  __shared__ __align__(16) ubf   htile[16*520];   // [16 b][512 + 8 pad]
  __shared__ __align__(16) ubf   ptile[16*136];   // [16 b][128 + 8 pad]
  __shared__ __align__(16) float ztile[16*132];   // [16 b][128 + 4 pad]

  int tid  = threadIdx.x;
  int wv   = tid >> 6;            // wave = gate index 0..3 (i,f,g,o)
  int lane = tid & 63, quad = lane >> 4, l16 = lane & 15;
  int bg   = blockIdx.x >> 4, cg = blockIdx.x & 15;
  int j0   = cg * 32;             // unit base

  // persistent Wh B-fragments: B[k][n], n = lane&15, k = quad*8+j
  short8 bfrag[2][16];
  #pragma unroll
  for (int h = 0; h < 2; h++){
    int col = wv*512 + j0 + h*16 + l16;
    #pragma unroll
    for (int kt = 0; kt < 16; kt++){
      short8 t8;
      #pragma unroll
      for (int j = 0; j < 8; j++){
        int k = kt*32 + quad*8 + j;
        t8[j] = (short)f2bf(Whf[(size_t)k * FOURH + col]);
      }
      bfrag[h][kt] = t8;
    }
  }

  float cst0 = 0.0f, cst1 = 0.0f;      // c-state for this thread's 2 (batch,unit) pairs
  int bl = tid >> 4;                   // local batch 0..15
  int up = (tid & 15) * 2;             // unit pair base within 32
  int bglob = bg*16 + bl;
  u32* htile32 = (u32*)htile;
  unsigned epoch0 = (unsigned)seg * 256u;

  for (int t = 0; t < 256; ++t){
    // stage P tile [16 b][4 gates x 32 units], gathered by action id
    {
      int act  = actions[(size_t)bglob * 256 + t];
      int colc = (tid & 15) * 8;
      int gate = colc >> 5, cw = colc & 31;
      uint4 q = *(const uint4*)(Pt + (size_t)act * FOURH + gate*512 + j0 + cw);
      *(uint4*)&ptile[bl*136 + colc] = q;
    }
    if (t > 0){
      if (tid < 16){
        unsigned tgt = epoch0 + (unsigned)t;
        while (__hip_atomic_load(&flags[(bg*16 + tid)*16], __ATOMIC_ACQUIRE,
                                 __HIP_MEMORY_SCOPE_AGENT) < tgt)
          __builtin_amdgcn_s_sleep(2);
      }
      __syncthreads();     // all threads wait until flags acquired
      const u32* src = (const u32*)(hbuf + (size_t)(((t+1)&1)*4 + bg) * 16 * 512);
      u32 tmp[16];
      #pragma unroll
      for (int i = 0; i < 16; i++)
        tmp[i] = __hip_atomic_load(&src[tid + 256*i], __ATOMIC_RELAXED, __HIP_MEMORY_SCOPE_AGENT);
      #pragma unroll
      for (int i = 0; i < 16; i++)
        htile32[i*260 + tid] = tmp[i];     // row i = batch, 260 u32/row (padded)
    }
    __syncthreads();

    f32x4 a0, a1;
    #pragma unroll
    for (int r = 0; r < 4; r++){ a0[r] = 0.0f; a1[r] = 0.0f; }
    if (t > 0){
      #pragma unroll
      for (int kt = 0; kt < 16; kt++){
        short8 af = *(const short8*)&htile[l16*520 + kt*32 + quad*8];
        a0 = __builtin_amdgcn_mfma_f32_16x16x32_bf16(af, bfrag[0][kt], a0, 0, 0, 0);
        a1 = __builtin_amdgcn_mfma_f32_16x16x32_bf16(af, bfrag[1][kt], a1, 0, 0, 0);
      }
    }
    // redistribute z via LDS so each thread gets matching i,f,g,o
    #pragma unroll
    for (int r = 0; r < 4; r++){
      ztile[(quad*4 + r)*132 + wv*32 + l16]      = a0[r];
      ztile[(quad*4 + r)*132 + wv*32 + 16 + l16] = a1[r];
    }
    __syncthreads();

    float m = mask ? mask[(size_t)bglob * 256 + t] : 1.0f;
    f2v ev;
    ubf hp[2];
    #pragma unroll
    for (int p = 0; p < 2; p++){
      int u = up + p;
      float zi = ztile[bl*132 +       u] + bf2f(ptile[bl*136 +       u]);
      float zf = ztile[bl*132 + 32 + u] + bf2f(ptile[bl*136 + 32 + u]);
      float zg = ztile[bl*132 + 64 + u] + bf2f(ptile[bl*136 + 64 + u]);
      float zo = ztile[bl*132 + 96 + u] + bf2f(ptile[bl*136 + 96 + u]);
      float is = sigm(zi), fs = sigm(zf), gt = tanh_fast(zg), os = sigm(zo);
      float cp = p ? cst1 : cst0;
      float cn = fs * cp + is * gt;
      float hn = os * tanh_fast(cn);
      ev[p] = hn;                       // enc records PRE-mask h (f32)
      float cm = m * cn;
      if (p) cst1 = cm; else cst0 = cm;
      hp[p] = f2bf(m * hn);             // masked h carried forward (bf16)
    }
    *(f2v*)(enc + ((size_t)bglob * 256 + t) * 512 + j0 + up) = ev;
    {
      u32 hword = (u32)hp[0] | ((u32)hp[1] << 16);
      u32* dst = (u32*)(hbuf + (size_t)((t&1)*4 + bg) * 16 * 512);
      __hip_atomic_store(&dst[(bl*512 + j0 + up) >> 1], hword,
                         __ATOMIC_RELAXED, __HIP_MEMORY_SCOPE_AGENT);
    }
    __threadfence();
    __syncthreads();
    if (tid == 0)
      __hip_atomic_store(&flags[(bg*16 + cg)*16], epoch0 + (unsigned)t + 1u,
                         __ATOMIC_RELEASE, __HIP_MEMORY_SCOPE_AGENT);
  }
}

// ---------------------------------------------------------------- softmax + cumsum + mask update (per batch)
__global__ __launch_bounds__(256, 4) void softmax_kernel(
    const float* __restrict__ part, const float* __restrict__ bb2, const float* __restrict__ gum,
    float* __restrict__ lout,
    float* __restrict__ sbf, float* __restrict__ sbout,
    float* __restrict__ logcum, float* __restrict__ maskf, float* __restrict__ maskout,
    int seg)
{
  __shared__ float red[256];
  __shared__ float cs[256];
  int b = blockIdx.x, t = threadIdx.x;
  float raw = 0.0f;
  #pragma unroll
  for (int s = 0; s < 8; s++) raw += part[s*16384 + b*256 + t];
  float lg  = (t == 0) ? NEG_INF_F : (raw + bb2[0]);
  lout[b*256 + t] = lg;
  float x = lg + gum[b*256 + t];   // TEMP_B = 1
  red[t] = x; __syncthreads();
  for (int o = 128; o > 0; o >>= 1){ if (t < o) red[t] = fmaxf(red[t], red[t+o]); __syncthreads(); }
  float mx = red[0]; __syncthreads();
  float e = __expf(x - mx);
  red[t] = e; __syncthreads();
  for (int o = 128; o > 0; o >>= 1){ if (t < o) red[t] += red[t+o]; __syncthreads(); }
  float s = red[0];
  float sb = e / s;
  sbf[b*256 + t] = sb;
  sbout[b*256 + t] = sb;
  // inclusive scan (Hillis-Steele)
  cs[t] = sb; __syncthreads();
  for (int o = 1; o < 256; o <<= 1){
    float v = cs[t];
    if (t >= o) v += cs[t - o];
    __syncthreads();
    cs[t] = v;
    __syncthreads();
  }
  float lc = logf(cs[t] + 1e-17f);
  float acc = (seg == 0) ? lc : (logcum[b*256 + t] + lc);
  logcum[b*256 + t] = acc;
  float mk = __expf(acc);
  maskf[b*256 + t] = mk;
  maskout[b*256 + t] = mk;
}

// ---------------------------------------------------------------- one-hot(lengths-1) (last segment)
__global__ void onehot_kernel(const int* __restrict__ lengths,
                              float* __restrict__ sbf, float* __restrict__ sbout)
{
  int b = blockIdx.x, t = threadIdx.x;
  float v = (t == (lengths[b] - 1)) ? 1.0f : 0.0f;
  sbf[b*256 + t] = v;
  sbout[b*256 + t] = v;
}

// ---------------------------------------------------------------- readout = sum_t enc[b,t]*sb[b,t+1]
__global__ __launch_bounds__(256, 4) void readout_kernel(
    const float* __restrict__ enc, const float* __restrict__ sbf, float* __restrict__ ro)
{
  __shared__ float sb[256];
  int b = blockIdx.x, tid = threadIdx.x;
  sb[tid] = sbf[b*256 + tid];
  __syncthreads();
  float a0 = 0.0f, a1 = 0.0f;
  for (int t = 0; t < 255; t++){
    float m = sb[t + 1];
    f2v q = *(const f2v*)(enc + ((size_t)b*256 + t)*512 + tid*2);
    a0 += m * q[0];
    a1 += m * q[1];
  }
  ro[b*512 + tid*2]     = a0;
  ro[b*512 + tid*2 + 1] = a1;
}

// ---------------------------------------------------------------- z-head + decoder (per batch)
// Writes pred into recs[seg] row (b, t=0) (f32); rec_kernel broadcasts t>=1.
__global__ __launch_bounds__(256, 2) void zdec_kernel(
    const float* __restrict__ ro,
    const float* __restrict__ Wz1, const float* __restrict__ bz1,
    const float* __restrict__ Wz2, const float* __restrict__ bz2,
    const float* __restrict__ epsz,
    const float* __restrict__ Wd1, const float* __restrict__ bd1,
    const float* __restrict__ Wd2, const float* __restrict__ bd2,
    float* __restrict__ lzout, float* __restrict__ szout, float* __restrict__ recseg)
{
  __shared__ float r[512], hz[512], lz[128], sz[64], hd[512];
  int b = blockIdx.x, tid = threadIdx.x;
  r[tid]       = ro[b*512 + tid];
  r[tid + 256] = ro[b*512 + tid + 256];
  __syncthreads();
  {
    float a0 = bz1[tid], a1 = bz1[tid + 256];
    for (int i = 0; i < 512; i++){
      float ri = r[i];
      a0 += ri * Wz1[(size_t)i*512 + tid];
      a1 += ri * Wz1[(size_t)i*512 + tid + 256];
    }
    hz[tid]       = fmaxf(a0, 0.0f);
    hz[tid + 256] = fmaxf(a1, 0.0f);
  }
  __syncthreads();
  if (tid < 128){
    float a = bz2[tid];
    for (int i = 0; i < 512; i++) a += hz[i] * Wz2[(size_t)i*128 + tid];
    lz[tid] = a;
    lzout[b*128 + tid] = a;
  }
  __syncthreads();
  if (tid < 64){
    float mu = lz[tid], lv = lz[64 + tid];
    float v = mu + __expf(0.5f * lv) * epsz[b*64 + tid];
    sz[tid] = v;
    szout[b*64 + tid] = v;
  }
  __syncthreads();
  {
    float a0 = bd1[tid], a1 = bd1[tid + 256];
    for (int l = 0; l < 64; l++){
      float s = sz[l];
      a0 += s * Wd1[l*512 + tid];
      a1 += s * Wd1[l*512 + tid + 256];
    }
    hd[tid]       = fmaxf(a0, 0.0f);
    hd[tid + 256] = fmaxf(a1, 0.0f);
  }
  __syncthreads();
  {
    float a0 = bd2[tid];
    float a1 = (tid < 244) ? bd2[tid + 256] : 0.0f;
    for (int h = 0; h < 512; h++){
      float hh = hd[h];
      a0 += hh * Wd2[(size_t)h*500 + tid];
      if (tid < 244) a1 += hh * Wd2[(size_t)h*500 + tid + 256];
    }
    recseg[(size_t)b*128000 + tid] = a0;
    if (tid < 244) recseg[(size_t)b*128000 + tid + 256] = a1;
  }
}

// ---------------------------------------------------------------- broadcast recs row (b,0) -> rows (b,t>=1)
__global__ void rec_kernel(float* __restrict__ outr)
{
  int bidx = blockIdx.x;
  int b = bidx >> 8, t = bidx & 255;
  if (t == 0) return;                       // row 0 already holds pred (written by zdec)
  int tid = threadIdx.x;
  if (tid < 125){
    f4v q = *(const f4v*)(outr + (size_t)b*128000 + tid*4);
    *(f4v*)(outr + ((size_t)b*256 + t)*500 + tid*4) = q;
  }
}

// ---------------------------------------------------------------- launcher
extern "C" void kernel_launch(void* const* d_in, const int* in_sizes, int n_in,
                              void* d_out, int out_size, void* d_ws, size_t ws_size,
                              hipStream_t stream)
{
  const int*   actions = (const int*)d_in[0];
  const int*   lengths = (const int*)d_in[1];
  const float* gumbel  = (const float*)d_in[2];
  const float* epsz    = (const float*)d_in[3];
  const float* embed   = (const float*)d_in[4];
  const float* Wx      = (const float*)d_in[5];
  const float* Wh      = (const float*)d_in[6];
  const float* b_lstm  = (const float*)d_in[7];
  const float* Wz1     = (const float*)d_in[8];
  const float* bz1     = (const float*)d_in[9];
  const float* Wz2     = (const float*)d_in[10];
  const float* bz2     = (const float*)d_in[11];
  const float* Wb1     = (const float*)d_in[12];
  const float* bb1     = (const float*)d_in[13];
  const float* Wb2     = (const float*)d_in[14];
  const float* bb2     = (const float*)d_in[15];
  const float* Wd1     = (const float*)d_in[16];
  const float* bd1     = (const float*)d_in[17];
  const float* Wd2     = (const float*)d_in[18];
  const float* bd2     = (const float*)d_in[19];
  float* out = (float*)d_out;

  // scratch in recs[2] f32 dead region
  float* r2      = out + (size_t)REC_OFF + 2*(size_t)REC_SEG;
  ubf*   P       = (ubf*)(r2 + SCR_P);         // bf16[512][2048]
  ubf*   hbuf    = (ubf*)(r2 + SCR_HBUF);      // bf16[2][4][16][512]
  u32*   flags   = (u32*)(r2 + SCR_FLAGS);
  float* maskf   = r2 + SCR_MASKF;
  float* logcum  = r2 + SCR_LOGCUM;
  float* partf   = r2 + SCR_PART;
  float* sbf     = r2 + SCR_SBF;
  float* rof     = r2 + SCR_ROF;

  hipLaunchKernelGGL(init_kernel, dim3(1), dim3(256), 0, stream, flags);

  // P[v] = embed[v] @ Wx + b_lstm  (f32 in -> bf16 table), computed once
  hipLaunchKernelGGL(gemm_kernel, dim3(16, 4), dim3(256), 0, stream,
                     (const void*)embed, 1, Wx, b_lstm, P,
                     (const float*)nullptr, (float*)nullptr,
                     512, 2048, 512, 0, 499);

  for (int seg = 0; seg < 3; ++seg){
    hipLaunchKernelGGL(lstm_kernel, dim3(64), dim3(256), 0, stream,
                       P, actions, Wh,
                       (seg == 0) ? (const float*)nullptr : maskf,
                       out + (size_t)seg * ENC_SEG, hbuf, flags, seg);
    const float* encc = out + (size_t)seg * ENC_SEG;
    if (seg < 2){
      // fused boundary head: partf[slice][m] = partial of relu(enc@Wb1+bb1).Wb2
      hipLaunchKernelGGL(gemm_kernel, dim3(4, 128), dim3(256), 0, stream,
                         (const void*)encc, 1, Wb1, bb1, (ubf*)nullptr, Wb2, partf,
                         16384, 512, 512, 1, 16383);
      hipLaunchKernelGGL(softmax_kernel, dim3(64), dim3(256), 0, stream,
                         partf, bb2, gumbel + (size_t)seg * 16384,
                         out + LOGB_OFF + (size_t)seg * 16384,
                         sbf, out + SAMB_OFF + (size_t)seg * 16384,
                         logcum, maskf, out + MASK_OFF + (size_t)seg * 16384, seg);
    } else {
      hipLaunchKernelGGL(onehot_kernel, dim3(64), dim3(256), 0, stream,
                         lengths, sbf, out + SAMB_OFF + (size_t)seg * 16384);
    }
    hipLaunchKernelGGL(readout_kernel, dim3(64), dim3(256), 0, stream, encc, sbf, rof);
    hipLaunchKernelGGL(zdec_kernel, dim3(64), dim3(256), 0, stream,
                       rof, Wz1, bz1, Wz2, bz2, epsz + (size_t)seg * 4096,
                       Wd1, bd1, Wd2, bd2,
                       out + LOGZ_OFF + (size_t)seg * 8192,
                       out + SAMZ_OFF + (size_t)seg * 4096,
                       out + REC_OFF + (size_t)seg * REC_SEG);
    hipLaunchKernelGGL(rec_kernel, dim3(16384), dim3(128), 0, stream,
                       out + REC_OFF + (size_t)seg * REC_SEG);
  }
  (void)in_sizes; (void)n_in; (void)out_size; (void)d_ws; (void)ws_size;
}

// Round 10
// 2883.628 us; speedup vs baseline: 2.2923x; 2.2923x over previous
//
#include <hip/hip_runtime.h>
#include <cstdint>
#include <cstddef>

typedef unsigned short ubf;   // bf16 bit pattern (internal use only)
typedef unsigned int   u32;
typedef __attribute__((ext_vector_type(8))) short short8;
typedef __attribute__((ext_vector_type(4))) float f32x4;
typedef __attribute__((ext_vector_type(4))) float f4v;
typedef __attribute__((ext_vector_type(2))) float f2v;
typedef __attribute__((ext_vector_type(4))) unsigned short us4;

#define NEG_INF_F (-1000000000.0f)
#define FOURH 2048

// d_out element offsets in FLOAT32 elements (confirmed r8/r9).
#define ENC_SEG   8388608            // 64*256*512
#define REC_OFF   25165824
#define REC_SEG   8192000            // 64*256*500
#define MASK_OFF  49741824
#define LOGB_OFF  49774592
#define SAMB_OFF  49807360
#define LOGZ_OFF  49856512
#define SAMZ_OFF  49881088

// scratch inside recs[2] dead region (f32 elements from region base); see r9 notes.
#define SCR_P       0               // bf16[512][2048] = 524,288 f32
#define SCR_HBUF    524288          // bf16[2][4][16][512] = 32,768 f32
#define SCR_FLAGS   557056          // 1,024 f32
#define SCR_MASKF   558080          // 16,384 f32
#define SCR_LOGCUM  574464          // 16,384 f32
#define SCR_PART    590848          // 131,072 f32
#define SCR_SBF     721920          // 16,384 f32
#define SCR_ROF     960000          // 32,768 f32 (stripe-free gap)

__device__ __forceinline__ float bf2f(ubf u){
  union { u32 i; float f; } v; v.i = ((u32)u) << 16; return v.f;
}
__device__ __forceinline__ ubf f2bf(float f){
  union { float f; u32 i; } v; v.f = f;
  u32 x = v.i;
  u32 r = (x + 0x7FFFu + ((x >> 16) & 1u)) >> 16;   // RNE
  return (ubf)r;
}
__device__ __forceinline__ float sigm(float x){
  return 1.0f / (1.0f + __expf(-x));
}
__device__ __forceinline__ float tanh_fast(float x){
  x = fminf(fmaxf(x, -20.0f), 20.0f);
  float e2 = __expf(2.0f * x);
  return (e2 - 1.0f) / (e2 + 1.0f);
}

// ---------------------------------------------------------------- init flags
__global__ void init_kernel(u32* flags){
  int tid = threadIdx.x;
  #pragma unroll
  for (int i = 0; i < 4; i++) flags[tid + i*256] = 0u;
}

// ---------------------------------------------------------------- GEMM (MFMA 16x16x32 bf16)
__global__ __launch_bounds__(256, 2) void gemm_kernel(
    const void* __restrict__ Aptr, int a_f32,
    const float* __restrict__ Bf, const float* __restrict__ bias,
    ubf* __restrict__ C, const float* __restrict__ wb2, float* __restrict__ part,
    int M, int N, int K, int relu, int mclamp)
{
  __shared__ __align__(16) ubf As[128*40];   // [128 rows][32 k + 8 pad]
  __shared__ __align__(16) ubf Bs[128*40];   // transposed: [128 n][32 k + 8 pad]
  int tid  = threadIdx.x;
  int bn   = blockIdx.x, bm = blockIdx.y;
  int w    = tid >> 6, lane = tid & 63, quad = lane >> 4, l16 = lane & 15;
  int wm   = w >> 1, wn = w & 1;

  f32x4 acc[4][4];
  #pragma unroll
  for (int i = 0; i < 4; i++)
    #pragma unroll
    for (int j = 0; j < 4; j++)
      #pragma unroll
      for (int r = 0; r < 4; r++) acc[i][j][r] = 0.0f;

  for (int k0 = 0; k0 < K; k0 += 32) {
    if (a_f32){
      const float* Af = (const float*)Aptr;
      #pragma unroll
      for (int h = 0; h < 4; h++){
        int v   = tid + h*256;          // 0..1023 float4 units
        int row = v >> 3, kc = (v & 7) * 4;
        int rm  = bm*128 + row;
        int ar  = rm < mclamp ? rm : mclamp;
        f4v q = *(const f4v*)(Af + (size_t)ar * K + k0 + kc);
        us4 s; s[0]=f2bf(q[0]); s[1]=f2bf(q[1]); s[2]=f2bf(q[2]); s[3]=f2bf(q[3]);
        *(us4*)&As[row*40 + kc] = s;
      }
    } else {
      const ubf* Ab = (const ubf*)Aptr;
      #pragma unroll
      for (int h = 0; h < 2; h++){
        int v   = tid + h*256;          // 0..511 vec8 units
        int row = v >> 2, kc = (v & 3) * 8;
        int rm  = bm*128 + row;
        int ar  = rm < mclamp ? rm : mclamp;
        uint4 q = *(const uint4*)(Ab + (size_t)ar * K + k0 + kc);
        *(uint4*)&As[row*40 + kc] = q;
      }
    }
    #pragma unroll
    for (int h = 0; h < 4; h++){
      int v  = tid + h*256;             // 0..1023 float4 units
      int kk = v >> 5, nn = (v & 31) * 4;
      f4v q = *(const f4v*)(Bf + (size_t)(k0 + kk) * N + bn*128 + nn);
      #pragma unroll
      for (int j = 0; j < 4; j++) Bs[(nn + j)*40 + kk] = f2bf(q[j]);
    }
    __syncthreads();
    short8 af[4], bfr[4];
    #pragma unroll
    for (int i = 0; i < 4; i++){
      int row = wm*64 + i*16 + l16;
      af[i]  = *(const short8*)&As[row*40 + quad*8];
      int col = wn*64 + i*16 + l16;
      bfr[i] = *(const short8*)&Bs[col*40 + quad*8];
    }
    #pragma unroll
    for (int i = 0; i < 4; i++)
      #pragma unroll
      for (int j = 0; j < 4; j++)
        acc[i][j] = __builtin_amdgcn_mfma_f32_16x16x32_bf16(af[i], bfr[j], acc[i][j], 0, 0, 0);
    __syncthreads();
  }
  if (!wb2){
    #pragma unroll
    for (int i = 0; i < 4; i++){
      #pragma unroll
      for (int j = 0; j < 4; j++){
        int n   = bn*128 + wn*64 + j*16 + l16;
        float bv = bias ? bias[n] : 0.0f;
        #pragma unroll
        for (int r = 0; r < 4; r++){
          int m   = bm*128 + wm*64 + i*16 + quad*4 + r;
          float vv = acc[i][j][r] + bv;
          if (relu) vv = fmaxf(vv, 0.0f);
          C[(size_t)m * N + n] = f2bf(vv);
        }
      }
    }
  } else {
    #pragma unroll
    for (int i = 0; i < 4; i++){
      f32x4 rp;
      #pragma unroll
      for (int r = 0; r < 4; r++) rp[r] = 0.0f;
      #pragma unroll
      for (int j = 0; j < 4; j++){
        int n   = bn*128 + wn*64 + j*16 + l16;
        float bv = bias[n];
        float wv = wb2[n];
        #pragma unroll
        for (int r = 0; r < 4; r++)
          rp[r] += fmaxf(acc[i][j][r] + bv, 0.0f) * wv;
      }
      #pragma unroll
      for (int off = 1; off < 16; off <<= 1)
        #pragma unroll
        for (int r = 0; r < 4; r++)
          rp[r] += __shfl_xor(rp[r], off, 64);
      if (l16 == 0){
        #pragma unroll
        for (int r = 0; r < 4; r++){
          int m = bm*128 + wm*64 + i*16 + quad*4 + r;
          part[(size_t)(bn*2 + wn)*16384 + m] = rp[r];
        }
      }
    }
  }
}

// ---------------------------------------------------------------- persistent masked-LSTM
// Fence-free cross-block protocol (r10): ALL cross-block traffic (hbuf, flags)
// uses RELAXED agent-scope atomics -> sc1-annotated ops, coherent at L3 with NO
// buffer_wbl2 / buffer_inv. r9's ACQUIRE spin invalidated the XCD L2 every poll
// (FETCH_SIZE 74.8 MB vs ~7 MB ideal, 7.3 us/step). Ordering: h sc1-stores ->
// __syncthreads (s_waitcnt vmcnt(0) drains before s_barrier) -> tid0 posts flag.
// Readers: RELAXED spin (no inv), then sc1 h-loads (L2 never holds hbuf lines).
__global__ __launch_bounds__(256, 1) void lstm_kernel(
    const ubf* __restrict__ Pt,      // [512(V pad)][4H] bf16, includes b_lstm
    const int* __restrict__ actions, // [B][T]
    const float* __restrict__ Whf,   // [H][4H] f32
    const float* __restrict__ mask,  // [B][T] f32 or null (seg 0)
    float* __restrict__ enc,         // d_out + seg*ENC_SEG (f32)
    ubf* hbuf,                       // scratch: [2][4][16][512] bf16
    u32* flags,                      // scratch: [64]x16-dword-padded
    int seg)
{
  __shared__ __align__(16) ubf   htile[16*520];   // [16 b][512 + 8 pad]
  __shared__ __align__(16) ubf   ptile[16*136];   // [16 b][128 + 8 pad]
  __shared__ __align__(16) float ztile[16*132];   // [16 b][128 + 4 pad]

  int tid  = threadIdx.x;
  int wv   = tid >> 6;            // wave = gate index 0..3 (i,f,g,o)
  int lane = tid & 63, quad = lane >> 4, l16 = lane & 15;
  int bg   = blockIdx.x >> 4, cg = blockIdx.x & 15;
  int j0   = cg * 32;             // unit base

  // persistent Wh B-fragments: B[k][n], n = lane&15, k = quad*8+j
  short8 bfrag[2][16];
  #pragma unroll
  for (int h = 0; h < 2; h++){
    int col = wv*512 + j0 + h*16 + l16;
    #pragma unroll
    for (int kt = 0; kt < 16; kt++){
      short8 t8;
      #pragma unroll
      for (int j = 0; j < 8; j++){
        int k = kt*32 + quad*8 + j;
        t8[j] = (short)f2bf(Whf[(size_t)k * FOURH + col]);
      }
      bfrag[h][kt] = t8;
    }
  }

  float cst0 = 0.0f, cst1 = 0.0f;      // c-state for this thread's 2 (batch,unit) pairs
  int bl = tid >> 4;                   // local batch 0..15
  int up = (tid & 15) * 2;             // unit pair base within 32
  int bglob = bg*16 + bl;
  u32* htile32 = (u32*)htile;
  unsigned epoch0 = (unsigned)seg * 256u;

  for (int t = 0; t < 256; ++t){
    // stage P tile [16 b][4 gates x 32 units], gathered by action id (L2-resident now)
    {
      int act  = actions[(size_t)bglob * 256 + t];
      int colc = (tid & 15) * 8;
      int gate = colc >> 5, cw = colc & 31;
      uint4 q = *(const uint4*)(Pt + (size_t)act * FOURH + gate*512 + j0 + cw);
      *(uint4*)&ptile[bl*136 + colc] = q;
    }
    if (t > 0){
      if (tid < 16){
        unsigned tgt = epoch0 + (unsigned)t;
        while (__hip_atomic_load(&flags[(bg*16 + tid)*16], __ATOMIC_RELAXED,
                                 __HIP_MEMORY_SCOPE_AGENT) < tgt)
          __builtin_amdgcn_s_sleep(1);
      }
      __syncthreads();     // all threads held until all 16 flags observed
      const u32* src = (const u32*)(hbuf + (size_t)(((t+1)&1)*4 + bg) * 16 * 512);
      u32 tmp[16];
      #pragma unroll
      for (int i = 0; i < 16; i++)
        tmp[i] = __hip_atomic_load(&src[tid + 256*i], __ATOMIC_RELAXED, __HIP_MEMORY_SCOPE_AGENT);
      #pragma unroll
      for (int i = 0; i < 16; i++)
        htile32[i*260 + tid] = tmp[i];     // row i = batch, 260 u32/row (padded)
    }
    __syncthreads();

    f32x4 a0, a1;
    #pragma unroll
    for (int r = 0; r < 4; r++){ a0[r] = 0.0f; a1[r] = 0.0f; }
    if (t > 0){
      #pragma unroll
      for (int kt = 0; kt < 16; kt++){
        short8 af = *(const short8*)&htile[l16*520 + kt*32 + quad*8];
        a0 = __builtin_amdgcn_mfma_f32_16x16x32_bf16(af, bfrag[0][kt], a0, 0, 0, 0);
        a1 = __builtin_amdgcn_mfma_f32_16x16x32_bf16(af, bfrag[1][kt], a1, 0, 0, 0);
      }
    }
    // redistribute z via LDS so each thread gets matching i,f,g,o
    #pragma unroll
    for (int r = 0; r < 4; r++){
      ztile[(quad*4 + r)*132 + wv*32 + l16]      = a0[r];
      ztile[(quad*4 + r)*132 + wv*32 + 16 + l16] = a1[r];
    }
    __syncthreads();

    float m = mask ? mask[(size_t)bglob * 256 + t] : 1.0f;
    f2v ev;
    ubf hp[2];
    #pragma unroll
    for (int p = 0; p < 2; p++){
      int u = up + p;
      float zi = ztile[bl*132 +       u] + bf2f(ptile[bl*136 +       u]);
      float zf = ztile[bl*132 + 32 + u] + bf2f(ptile[bl*136 + 32 + u]);
      float zg = ztile[bl*132 + 64 + u] + bf2f(ptile[bl*136 + 64 + u]);
      float zo = ztile[bl*132 + 96 + u] + bf2f(ptile[bl*136 + 96 + u]);
      float is = sigm(zi), fs = sigm(zf), gt = tanh_fast(zg), os = sigm(zo);
      float cp = p ? cst1 : cst0;
      float cn = fs * cp + is * gt;
      float hn = os * tanh_fast(cn);
      ev[p] = hn;                       // enc records PRE-mask h (f32)
      float cm = m * cn;
      if (p) cst1 = cm; else cst0 = cm;
      hp[p] = f2bf(m * hn);             // masked h carried forward (bf16)
    }
    *(f2v*)(enc + ((size_t)bglob * 256 + t) * 512 + j0 + up) = ev;
    {
      u32 hword = (u32)hp[0] | ((u32)hp[1] << 16);
      u32* dst = (u32*)(hbuf + (size_t)((t&1)*4 + bg) * 16 * 512);
      __hip_atomic_store(&dst[(bl*512 + j0 + up) >> 1], hword,
                         __ATOMIC_RELAXED, __HIP_MEMORY_SCOPE_AGENT);
    }
    __threadfence_block();   // ordering intent only (block scope: no cache ops)
    __syncthreads();         // drains vmcnt(0): sc1 h-stores committed at L3
    if (tid == 0)
      __hip_atomic_store(&flags[(bg*16 + cg)*16], epoch0 + (unsigned)t + 1u,
                         __ATOMIC_RELAXED, __HIP_MEMORY_SCOPE_AGENT);
  }
}

// ---------------------------------------------------------------- softmax + cumsum + mask update (per batch)
__global__ __launch_bounds__(256, 4) void softmax_kernel(
    const float* __restrict__ part, const float* __restrict__ bb2, const float* __restrict__ gum,
    float* __restrict__ lout,
    float* __restrict__ sbf, float* __restrict__ sbout,
    float* __restrict__ logcum, float* __restrict__ maskf, float* __restrict__ maskout,
    int seg)
{
  __shared__ float red[256];
  __shared__ float cs[256];
  int b = blockIdx.x, t = threadIdx.x;
  float raw = 0.0f;
  #pragma unroll
  for (int s = 0; s < 8; s++) raw += part[s*16384 + b*256 + t];
  float lg  = (t == 0) ? NEG_INF_F : (raw + bb2[0]);
  lout[b*256 + t] = lg;
  float x = lg + gum[b*256 + t];   // TEMP_B = 1
  red[t] = x; __syncthreads();
  for (int o = 128; o > 0; o >>= 1){ if (t < o) red[t] = fmaxf(red[t], red[t+o]); __syncthreads(); }
  float mx = red[0]; __syncthreads();
  float e = __expf(x - mx);
  red[t] = e; __syncthreads();
  for (int o = 128; o > 0; o >>= 1){ if (t < o) red[t] += red[t+o]; __syncthreads(); }
  float s = red[0];
  float sb = e / s;
  sbf[b*256 + t] = sb;
  sbout[b*256 + t] = sb;
  cs[t] = sb; __syncthreads();
  for (int o = 1; o < 256; o <<= 1){
    float v = cs[t];
    if (t >= o) v += cs[t - o];
    __syncthreads();
    cs[t] = v;
    __syncthreads();
  }
  float lc = logf(cs[t] + 1e-17f);
  float acc = (seg == 0) ? lc : (logcum[b*256 + t] + lc);
  logcum[b*256 + t] = acc;
  float mk = __expf(acc);
  maskf[b*256 + t] = mk;
  maskout[b*256 + t] = mk;
}

// ---------------------------------------------------------------- one-hot(lengths-1) (last segment)
__global__ void onehot_kernel(const int* __restrict__ lengths,
                              float* __restrict__ sbf, float* __restrict__ sbout)
{
  int b = blockIdx.x, t = threadIdx.x;
  float v = (t == (lengths[b] - 1)) ? 1.0f : 0.0f;
  sbf[b*256 + t] = v;
  sbout[b*256 + t] = v;
}

// ---------------------------------------------------------------- readout = sum_t enc[b,t]*sb[b,t+1]
__global__ __launch_bounds__(256, 4) void readout_kernel(
    const float* __restrict__ enc, const float* __restrict__ sbf, float* __restrict__ ro)
{
  __shared__ float sb[256];
  int b = blockIdx.x, tid = threadIdx.x;
  sb[tid] = sbf[b*256 + tid];
  __syncthreads();
  float a0 = 0.0f, a1 = 0.0f;
  for (int t = 0; t < 255; t++){
    float m = sb[t + 1];
    f2v q = *(const f2v*)(enc + ((size_t)b*256 + t)*512 + tid*2);
    a0 += m * q[0];
    a1 += m * q[1];
  }
  ro[b*512 + tid*2]     = a0;
  ro[b*512 + tid*2 + 1] = a1;
}

// ---------------------------------------------------------------- z-head + decoder (per batch)
__global__ __launch_bounds__(256, 2) void zdec_kernel(
    const float* __restrict__ ro,
    const float* __restrict__ Wz1, const float* __restrict__ bz1,
    const float* __restrict__ Wz2, const float* __restrict__ bz2,
    const float* __restrict__ epsz,
    const float* __restrict__ Wd1, const float* __restrict__ bd1,
    const float* __restrict__ Wd2, const float* __restrict__ bd2,
    float* __restrict__ lzout, float* __restrict__ szout, float* __restrict__ recseg)
{
  __shared__ float r[512], hz[512], lz[128], sz[64], hd[512];
  int b = blockIdx.x, tid = threadIdx.x;
  r[tid]       = ro[b*512 + tid];
  r[tid + 256] = ro[b*512 + tid + 256];
  __syncthreads();
  {
    float a0 = bz1[tid], a1 = bz1[tid + 256];
    for (int i = 0; i < 512; i++){
      float ri = r[i];
      a0 += ri * Wz1[(size_t)i*512 + tid];
      a1 += ri * Wz1[(size_t)i*512 + tid + 256];
    }
    hz[tid]       = fmaxf(a0, 0.0f);
    hz[tid + 256] = fmaxf(a1, 0.0f);
  }
  __syncthreads();
  if (tid < 128){
    float a = bz2[tid];
    for (int i = 0; i < 512; i++) a += hz[i] * Wz2[(size_t)i*128 + tid];
    lz[tid] = a;
    lzout[b*128 + tid] = a;
  }
  __syncthreads();
  if (tid < 64){
    float mu = lz[tid], lv = lz[64 + tid];
    float v = mu + __expf(0.5f * lv) * epsz[b*64 + tid];
    sz[tid] = v;
    szout[b*64 + tid] = v;
  }
  __syncthreads();
  {
    float a0 = bd1[tid], a1 = bd1[tid + 256];
    for (int l = 0; l < 64; l++){
      float s = sz[l];
      a0 += s * Wd1[l*512 + tid];
      a1 += s * Wd1[l*512 + tid + 256];
    }
    hd[tid]       = fmaxf(a0, 0.0f);
    hd[tid + 256] = fmaxf(a1, 0.0f);
  }
  __syncthreads();
  {
    float a0 = bd2[tid];
    float a1 = (tid < 244) ? bd2[tid + 256] : 0.0f;
    for (int h = 0; h < 512; h++){
      float hh = hd[h];
      a0 += hh * Wd2[(size_t)h*500 + tid];
      if (tid < 244) a1 += hh * Wd2[(size_t)h*500 + tid + 256];
    }
    recseg[(size_t)b*128000 + tid] = a0;
    if (tid < 244) recseg[(size_t)b*128000 + tid + 256] = a1;
  }
}

// ---------------------------------------------------------------- broadcast recs row (b,0) -> rows (b,t>=1)
__global__ void rec_kernel(float* __restrict__ outr)
{
  int bidx = blockIdx.x;
  int b = bidx >> 8, t = bidx & 255;
  if (t == 0) return;
  int tid = threadIdx.x;
  if (tid < 125){
    f4v q = *(const f4v*)(outr + (size_t)b*128000 + tid*4);
    *(f4v*)(outr + ((size_t)b*256 + t)*500 + tid*4) = q;
  }
}

// ---------------------------------------------------------------- launcher
extern "C" void kernel_launch(void* const* d_in, const int* in_sizes, int n_in,
                              void* d_out, int out_size, void* d_ws, size_t ws_size,
                              hipStream_t stream)
{
  const int*   actions = (const int*)d_in[0];
  const int*   lengths = (const int*)d_in[1];
  const float* gumbel  = (const float*)d_in[2];
  const float* epsz    = (const float*)d_in[3];
  const float* embed   = (const float*)d_in[4];
  const float* Wx      = (const float*)d_in[5];
  const float* Wh      = (const float*)d_in[6];
  const float* b_lstm  = (const float*)d_in[7];
  const float* Wz1     = (const float*)d_in[8];
  const float* bz1     = (const float*)d_in[9];
  const float* Wz2     = (const float*)d_in[10];
  const float* bz2     = (const float*)d_in[11];
  const float* Wb1     = (const float*)d_in[12];
  const float* bb1     = (const float*)d_in[13];
  const float* Wb2     = (const float*)d_in[14];
  const float* bb2     = (const float*)d_in[15];
  const float* Wd1     = (const float*)d_in[16];
  const float* bd1     = (const float*)d_in[17];
  const float* Wd2     = (const float*)d_in[18];
  const float* bd2     = (const float*)d_in[19];
  float* out = (float*)d_out;

  float* r2      = out + (size_t)REC_OFF + 2*(size_t)REC_SEG;
  ubf*   P       = (ubf*)(r2 + SCR_P);
  ubf*   hbuf    = (ubf*)(r2 + SCR_HBUF);
  u32*   flags   = (u32*)(r2 + SCR_FLAGS);
  float* maskf   = r2 + SCR_MASKF;
  float* logcum  = r2 + SCR_LOGCUM;
  float* partf   = r2 + SCR_PART;
  float* sbf     = r2 + SCR_SBF;
  float* rof     = r2 + SCR_ROF;

  hipLaunchKernelGGL(init_kernel, dim3(1), dim3(256), 0, stream, flags);

  hipLaunchKernelGGL(gemm_kernel, dim3(16, 4), dim3(256), 0, stream,
                     (const void*)embed, 1, Wx, b_lstm, P,
                     (const float*)nullptr, (float*)nullptr,
                     512, 2048, 512, 0, 499);

  for (int seg = 0; seg < 3; ++seg){
    hipLaunchKernelGGL(lstm_kernel, dim3(64), dim3(256), 0, stream,
                       P, actions, Wh,
                       (seg == 0) ? (const float*)nullptr : maskf,
                       out + (size_t)seg * ENC_SEG, hbuf, flags, seg);
    const float* encc = out + (size_t)seg * ENC_SEG;
    if (seg < 2){
      hipLaunchKernelGGL(gemm_kernel, dim3(4, 128), dim3(256), 0, stream,
                         (const void*)encc, 1, Wb1, bb1, (ubf*)nullptr, Wb2, partf,
                         16384, 512, 512, 1, 16383);
      hipLaunchKernelGGL(softmax_kernel, dim3(64), dim3(256), 0, stream,
                         partf, bb2, gumbel + (size_t)seg * 16384,
                         out + LOGB_OFF + (size_t)seg * 16384,
                         sbf, out + SAMB_OFF + (size_t)seg * 16384,
                         logcum, maskf, out + MASK_OFF + (size_t)seg * 16384, seg);
    } else {
      hipLaunchKernelGGL(onehot_kernel, dim3(64), dim3(256), 0, stream,
                         lengths, sbf, out + SAMB_OFF + (size_t)seg * 16384);
    }
    hipLaunchKernelGGL(readout_kernel, dim3(64), dim3(256), 0, stream, encc, sbf, rof);
    hipLaunchKernelGGL(zdec_kernel, dim3(64), dim3(256), 0, stream,
                       rof, Wz1, bz1, Wz2, bz2, epsz + (size_t)seg * 4096,
                       Wd1, bd1, Wd2, bd2,
                       out + LOGZ_OFF + (size_t)seg * 8192,
                       out + SAMZ_OFF + (size_t)seg * 4096,
                       out + REC_OFF + (size_t)seg * REC_SEG);
    hipLaunchKernelGGL(rec_kernel, dim3(16384), dim3(128), 0, stream,
                       out + REC_OFF + (size_t)seg * REC_SEG);
  }
  (void)in_sizes; (void)n_in; (void)out_size; (void)d_ws; (void)ws_size;
}